// Round 10
// baseline (387.274 us; speedup 1.0000x reference)
//
#include <hip/hip_runtime.h>
#include <hip/hip_bf16.h>
#include <stdint.h>

// LearnableCorrBlock: fmap1/2 [2,256,64,64] f32, coords [2,2,64,64], raw_P [256,256], raw_D [256]
// out [2, 4*81, 64, 64] f32.
//
//  - W-chain: P = (I+S)^2 (I+S^2)(I+S^4)  (Neumann, err ~||S||^8 ~ 4e-7); Wms = P^T D P /16
//  - g1[b,i,c] = f1^T Wms (bf16), coalesced via LDS transpose (512 blocks, 2/CU)
//  - t_l[b,y,x,c] = pooled fmap2, bf16; coalesced read + LDS transpose write
//  - sampler v5: 32-lane cooperative dots. Round 9 post-mortem: p-major per-lane dots gave
//    each lane a DIFFERENT t-row (queries have different X0/Y0) -> every wave load touched
//    ~64 cache lines, address-serialized in TA/L2 (VALUBusy 10%, 162us). Now one dot per
//    32-lane group: lane l reads 16B of the 512B row (fully coalesced), 4-deep dot2 chain,
//    5-step shfl_xor reduce; per-thread q constant -> g1 fragment hoisted to registers.
//    NOTE: no min-waves launch_bounds hint (round 5: forced 64 VGPR -> 217MB spill traffic).

#define DIM 256
#define HH 64
#define WW 64
#define HW 4096
#define NB 2
#define NQ 8192
#define NCH 324
#define QB 4

__device__ __constant__ size_t c_toff[4] = {0, 2097152, 2621440, 2752512};

static __device__ __forceinline__ unsigned short f2bf(float f) {
    unsigned int u = __float_as_uint(f);
    unsigned int r = (u + 0x7fffu + ((u >> 16) & 1u)) >> 16;   // RNE
    return (unsigned short)r;
}
static __device__ __forceinline__ float bflo(unsigned int u) { return __uint_as_float(u << 16); }
static __device__ __forceinline__ float bfhi(unsigned int u) { return __uint_as_float(u & 0xffff0000u); }

#if __has_builtin(__builtin_amdgcn_fdot2_f32_bf16)
typedef __bf16 bf16x2_t __attribute__((ext_vector_type(2)));
#define HAVE_DOT2 1
static __device__ __forceinline__ float dot2bf(unsigned int a, unsigned int b, float c) {
    return __builtin_amdgcn_fdot2_f32_bf16(__builtin_bit_cast(bf16x2_t, a),
                                           __builtin_bit_cast(bf16x2_t, b), c, false);
}
#else
#define HAVE_DOT2 0
#endif

// ---------- 1. prep: skew S and diagonal dvec ----------
__global__ void prep_kernel(const float* __restrict__ rp, const float* __restrict__ rd,
                            float* __restrict__ S, float* __restrict__ dvec) {
    int i = blockIdx.x, j = threadIdx.x;
    float v = 0.f;
    if (j > i)      v =  0.5f * rp[i * DIM + j];
    else if (j < i) v = -0.5f * rp[j * DIM + i];
    S[i * DIM + j] = v;
    if (i == 0) {
        float t = atanf(rd[j]) * 0.63661977236758134f;  // 2/pi
        dvec[j] = (1.0f + t) / (1.0f - t);
    }
}

// ---------- 2. row-per-block GEMMs (A-row uniform -> s_loads; B coalesced) ----------
__global__ __launch_bounds__(256) void gemm_plain(const float* __restrict__ A,
                                                  const float* __restrict__ B,
                                                  float* __restrict__ C) {
    int i = blockIdx.x, j = threadIdx.x;
    const float* a = A + (size_t)i * DIM;
    float acc = 0.f;
#pragma unroll 8
    for (int k = 0; k < DIM; ++k) acc += a[k] * B[k * DIM + j];
    C[i * DIM + j] = acc;
}

// U = (I + 2S + M2) @ (I + M2)
__global__ __launch_bounds__(256) void gemm_U(const float* __restrict__ S,
                                              const float* __restrict__ M2,
                                              float* __restrict__ U) {
    int i = blockIdx.x, j = threadIdx.x;
    const float* s = S + (size_t)i * DIM;
    const float* m = M2 + (size_t)i * DIM;
    float acc = 0.f;
#pragma unroll 8
    for (int k = 0; k < DIM; ++k) {
        float av = 2.f * s[k] + m[k] + ((k == i) ? 1.f : 0.f);
        acc += av * M2[k * DIM + j];
    }
    acc += 2.f * s[j] + m[j] + ((j == i) ? 1.f : 0.f);
    U[i * DIM + j] = acc;
}

// P = U @ (I + M4)
__global__ __launch_bounds__(256) void gemm_P(const float* __restrict__ U,
                                              const float* __restrict__ M4,
                                              float* __restrict__ P) {
    int i = blockIdx.x, j = threadIdx.x;
    const float* a = U + (size_t)i * DIM;
    float acc = 0.f;
#pragma unroll 8
    for (int k = 0; k < DIM; ++k) acc += a[k] * M4[k * DIM + j];
    acc += a[j];
    P[i * DIM + j] = acc;
}

// ---------- 3. Wms[i,j] = sum_k P[k,i]*d[k]*P[k,j] / 16 (LDS-staged column) ----------
__global__ __launch_bounds__(256) void gemmW_kernel(const float* __restrict__ P,
                                                    const float* __restrict__ dvec,
                                                    float* __restrict__ Wms) {
    __shared__ float col[DIM];
    int i = blockIdx.x, j = threadIdx.x;
    col[j] = P[j * DIM + i] * dvec[j];
    __syncthreads();
    float acc = 0.f;
#pragma unroll 8
    for (int k = 0; k < DIM; ++k) acc += col[k] * P[k * DIM + j];
    Wms[i * DIM + j] = acc * 0.0625f;
}

// ---------- 4. g1[b,i,c] = sum_c' f1[b,c',i] * Wms[c',c]  (bf16, coalesced store) ----------
// grid dim3(64, 4, 2): i-tile 64, c-tile 64 -> 512 blocks (2/CU, 8 waves/CU)
__global__ __launch_bounds__(256) void g1_kernel(const float* __restrict__ f1,
                                                 const float* __restrict__ Wms,
                                                 unsigned int* __restrict__ g1u) {
    __shared__ unsigned int lt[64][33];
    int b = blockIdx.z;
    int tid = threadIdx.x;
    int il = tid & 63, w = tid >> 6;
    int i = blockIdx.x * 64 + il;
    int cb = blockIdx.y * 64 + w * 16;      // wave-uniform
    const float* f1p = f1 + (size_t)b * DIM * HW + i;
    float acc[16];
#pragma unroll
    for (int c = 0; c < 16; ++c) acc[c] = 0.f;
#pragma unroll 4
    for (int cp = 0; cp < DIM; ++cp) {
        float a = f1p[(size_t)cp * HW];
        const float* wrow = Wms + cp * DIM + cb;  // wave-uniform -> scalar loads
#pragma unroll
        for (int c = 0; c < 16; ++c) acc[c] += a * wrow[c];
    }
#pragma unroll
    for (int m = 0; m < 8; ++m) {
        unsigned int u = (unsigned int)f2bf(acc[2 * m]) | ((unsigned int)f2bf(acc[2 * m + 1]) << 16);
        lt[il][w * 8 + m] = u;
    }
    __syncthreads();
    unsigned int* dst = g1u + ((size_t)b * HW + blockIdx.x * 64) * 128 + blockIdx.y * 32;
#pragma unroll
    for (int j2 = 0; j2 < 8; ++j2) {
        int idx = tid + 256 * j2;
        int row = idx >> 5, cu = idx & 31;
        dst[(size_t)row * 128 + cu] = lt[row][cu];
    }
}

// ---------- 5. pooled + transposed f2 -> t_l[b,y,x,c] bf16 (coalesced both sides) ----------
__global__ __launch_bounds__(256) void pool_kernel(const float* __restrict__ f2,
                                                   unsigned short* __restrict__ t) {
    __shared__ unsigned short tile[64][258];
    int b = blockIdx.y;
    int r = blockIdx.x;
    int lvl, y;
    if (r < 64)       { lvl = 0; y = r; }
    else if (r < 96)  { lvl = 1; y = r - 64; }
    else if (r < 112) { lvl = 2; y = r - 96; }
    else              { lvl = 3; y = r - 112; }
    int wl = 64 >> lvl;            // 64,32,16,8
    int s = 1 << lvl;
    int shift = 6 - lvl;           // log2(wl)
    int ncg = 4 << lvl;            // 256/wl
    float inv = 1.0f / (float)(s * s);
    int tid = threadIdx.x;
    int xl = tid & (wl - 1);
    int cg = tid >> shift;

    for (int c = cg; c < DIM; c += ncg) {
        const float* src = f2 + (((size_t)b * DIM + c) * HH + y * s) * WW + xl * s;
        float acc = 0.f;
        for (int dy = 0; dy < s; ++dy) {
            const float* rowp = src + dy * WW;
            if (s == 1)      acc += rowp[0];
            else if (s == 2) { float2 v = *(const float2*)rowp; acc += v.x + v.y; }
            else if (s == 4) { float4 v = *(const float4*)rowp; acc += v.x + v.y + v.z + v.w; }
            else             { float4 v0 = *(const float4*)rowp; float4 v1 = *(const float4*)(rowp + 4);
                               acc += (v0.x + v0.y + v0.z + v0.w) + (v1.x + v1.y + v1.z + v1.w); }
        }
        tile[xl][c] = f2bf(acc * inv);
    }
    __syncthreads();
    unsigned short* dstbase = t + c_toff[lvl] + (((size_t)b * wl + y) * (size_t)wl) * DIM;
    int cu = tid & 127, xr = tid >> 7;
    for (int p0 = 0; p0 < wl; p0 += 2) {
        int xw = p0 + xr;
        unsigned int val = (unsigned int)tile[xw][2 * cu] | ((unsigned int)tile[xw][2 * cu + 1] << 16);
        *(unsigned int*)(dstbase + (size_t)xw * DIM + 2 * cu) = val;
    }
}

// ---------- 6. sampler v5: 32-lane cooperative dots, coalesced 512B row loads ----------
__global__ __launch_bounds__(256) void sample_kernel(const unsigned short* __restrict__ g1,
                                                     const unsigned short* __restrict__ t,
                                                     const float* __restrict__ coords,
                                                     float* __restrict__ out) {
#if HAVE_DOT2
    __shared__ __align__(16) unsigned int gu[QB][132];
#else
    __shared__ __align__(16) float gf[QB][260];
#endif
    __shared__ float Dl[QB][401];
    __shared__ float cxs[QB], cys[QB];

    int bid = blockIdx.x;
    int swz = (bid & 7) * 256 + (bid >> 3);   // bijective XCD swizzle, 2048 blocks
    int qbase = swz * QB;
    int b = qbase >> 12, y = (qbase >> 6) & 63, x0 = qbase & 63;
    int tid = threadIdx.x;

    if (tid < QB * 32) {   // QB g1 rows = QB*256 bf16 = QB*32 uint4
        const uint4* src = (const uint4*)(g1 + (size_t)qbase * DIM);
        uint4 wv = src[tid];
#if HAVE_DOT2
        *(uint4*)&gu[tid >> 5][(tid & 31) * 4] = wv;
#else
        float* dst = &gf[tid >> 5][(tid & 31) * 8];
        dst[0] = bflo(wv.x); dst[1] = bfhi(wv.x);
        dst[2] = bflo(wv.y); dst[3] = bfhi(wv.y);
        dst[4] = bflo(wv.z); dst[5] = bfhi(wv.z);
        dst[6] = bflo(wv.w); dst[7] = bfhi(wv.w);
#endif
    }
    if (tid < QB) {
        cxs[tid] = coords[(((size_t)b * 2 + 0) * HH + y) * WW + (x0 + tid)];
        cys[tid] = coords[(((size_t)b * 2 + 1) * HH + y) * WW + (x0 + tid)];
    }
    __syncthreads();

    int l = tid & 31;          // lane within group
    int g = tid >> 5;          // group 0..7
    int q = g & 3;             // constant per thread
    int phi = g >> 2;          // 0 or 1
    float cx = cxs[q], cy = cys[q];
#if HAVE_DOT2
    uint4 gv = *(const uint4*)&gu[q][l * 4];        // hoisted g1 fragment (16B of row q)
#else
    float4 ga = *(const float4*)&gf[q][l * 8];
    float4 gb = *(const float4*)&gf[q][l * 8 + 4];
#endif

    // phase 1: 1600 dots; group (q,phi) handles p = 2*it + phi
    for (int it = 0; it < 200; ++it) {
        int p = it * 2 + phi;             // 0..399
        int lvl = p / 100, rem = p % 100;
        int u = rem / 10, v = rem % 10;
        float scale = 1.0f / (float)(1 << lvl);
        float cxl = cx * scale, cyl = cy * scale;
        int X0 = (int)floorf(cxl), Y0 = (int)floorf(cyl);
        int wl = 64 >> lvl;
        int xi = X0 - 4 + u, yi = Y0 - 4 + v;
        float r = 0.f;
        if (xi >= 0 && xi < wl && yi >= 0 && yi < wl) {   // group-uniform branch
            const uint4* tv = (const uint4*)(t + c_toff[lvl] + (((size_t)b * wl + yi) * (size_t)wl + xi) * DIM);
            uint4 wv = tv[l];             // lane l: bytes [16l,16l+16) of the 512B row
#if HAVE_DOT2
            float a = dot2bf(wv.x, gv.x, 0.f);
            a = dot2bf(wv.y, gv.y, a);
            a = dot2bf(wv.z, gv.z, a);
            a = dot2bf(wv.w, gv.w, a);
            r = a;
#else
            float a0 = bflo(wv.x) * ga.x + bfhi(wv.x) * ga.y;
            float a1 = bflo(wv.y) * ga.z + bfhi(wv.y) * ga.w;
            float a2 = bflo(wv.z) * gb.x + bfhi(wv.z) * gb.y;
            float a3 = bflo(wv.w) * gb.z + bfhi(wv.w) * gb.w;
            r = (a0 + a1) + (a2 + a3);
#endif
            // 5-step butterfly within the 32-lane group (all lanes active here)
            r += __shfl_xor(r, 16);
            r += __shfl_xor(r, 8);
            r += __shfl_xor(r, 4);
            r += __shfl_xor(r, 2);
            r += __shfl_xor(r, 1);
        }
        if (l == 0) Dl[q][p] = r;
    }
    __syncthreads();

    // phase 2: QB*324 outputs; idx = ch*QB + q
    for (int idx = tid; idx < QB * NCH; idx += 256) {
        int ch = idx >> 2, qq = idx & (QB - 1);
        int lvl = ch / 81, rem2 = ch % 81;
        int a = rem2 / 9, bb = rem2 % 9;
        float cx2 = cxs[qq], cy2 = cys[qq];
        float scale = 1.0f / (float)(1 << lvl);
        float cxl = cx2 * scale, cyl = cy2 * scale;
        float fx = cxl - floorf(cxl), fy = cyl - floorf(cyl);
        float wx0 = 1.f - fx, wy0 = 1.f - fy;
        int base = lvl * 100 + a * 10 + bb;
        float v00 = Dl[qq][base],     v10 = Dl[qq][base + 10];
        float v01 = Dl[qq][base + 1], v11 = Dl[qq][base + 11];
        float val = wy0 * (wx0 * v00 + fx * v10) + fy * (wx0 * v01 + fx * v11);
        out[(((size_t)b * NCH + ch) * HH + y) * WW + (x0 + qq)] = val;
    }
}

extern "C" void kernel_launch(void* const* d_in, const int* in_sizes, int n_in,
                              void* d_out, int out_size, void* d_ws, size_t ws_size,
                              hipStream_t stream) {
    const float* f1     = (const float*)d_in[0];
    const float* f2     = (const float*)d_in[1];
    const float* coords = (const float*)d_in[2];
    const float* rp     = (const float*)d_in[3];
    const float* rd     = (const float*)d_in[4];
    float* out = (float*)d_out;

    // workspace carve (floats)
    float* S    = (float*)d_ws;
    float* M2   = S   + 65536;
    float* M4   = M2  + 65536;
    float* Um   = M4  + 65536;
    float* Pm   = Um  + 65536;
    float* Wms  = Pm  + 65536;
    float* dvec = Wms + 65536;                               // 256 floats
    unsigned short* g1 = (unsigned short*)(dvec + 256);      // 2*4096*256 bf16
    unsigned short* t  = g1 + (size_t)NB * HW * DIM;         // 2785280 bf16

    prep_kernel<<<256, 256, 0, stream>>>(rp, rd, S, dvec);
    gemm_plain<<<256, 256, 0, stream>>>(S,  S,  M2);     // S^2
    gemm_plain<<<256, 256, 0, stream>>>(M2, M2, M4);     // S^4
    gemm_U    <<<256, 256, 0, stream>>>(S,  M2, Um);     // (I+S)^2 (I+S^2)
    gemm_P    <<<256, 256, 0, stream>>>(Um, M4, Pm);     // * (I+S^4) = P
    gemmW_kernel<<<256, 256, 0, stream>>>(Pm, dvec, Wms);

    g1_kernel<<<dim3(64, 4, 2), 256, 0, stream>>>(f1, Wms, (unsigned int*)g1);
    pool_kernel<<<dim3(120, 2), 256, 0, stream>>>(f2, t);
    sample_kernel<<<NQ / QB, 256, 0, stream>>>(g1, t, coords, out);
}

// Round 15
// 272.544 us; speedup vs baseline: 1.4210x; 1.4210x over previous
//
#include <hip/hip_runtime.h>
#include <hip/hip_bf16.h>
#include <stdint.h>

// LearnableCorrBlock: fmap1/2 [2,256,64,64] f32, coords [2,2,64,64], raw_P [256,256], raw_D [256]
// out [2, 4*81, 64, 64] f32.
//
//  - W-chain: P = (I+S)^2 (I+S^2)(I+S^4)  (Neumann); Wms = P^T D P /16
//  - g1[b,i,c] = f1^T Wms (bf16); t_l[b,y,x,c] = pooled fmap2 bf16
//  - sampler v6: one wave per query. Round-10 post-mortem: v5's 32-lane coop dots were
//    VALU-bound on overhead (84% busy, 61 inst/dot: 5-step shfl + per-dot decode + 16-VGPR
//    rematerialization). v6: per-wave LDS table of precomputed row offsets (decode once),
//    4-lane quads per dot (8x uint4 coalesced 64B/quad loads, 32 in-lane dot2, 2-step shfl),
//    g1 fragment pinned in 32 VGPRs. ~3.4 inst/dot; L2-BW floor ~48us.
//    NOTE: no min-waves launch_bounds hint (round 5: forced 64 VGPR -> 217MB spill traffic).

#define DIM 256
#define HH 64
#define WW 64
#define HW 4096
#define NB 2
#define NQ 8192
#define NCH 324
#define QB 4

__device__ __constant__ size_t c_toff[4] = {0, 2097152, 2621440, 2752512};

static __device__ __forceinline__ unsigned short f2bf(float f) {
    unsigned int u = __float_as_uint(f);
    unsigned int r = (u + 0x7fffu + ((u >> 16) & 1u)) >> 16;   // RNE
    return (unsigned short)r;
}
static __device__ __forceinline__ float bflo(unsigned int u) { return __uint_as_float(u << 16); }
static __device__ __forceinline__ float bfhi(unsigned int u) { return __uint_as_float(u & 0xffff0000u); }

#if __has_builtin(__builtin_amdgcn_fdot2_f32_bf16)
typedef __bf16 bf16x2_t __attribute__((ext_vector_type(2)));
#define HAVE_DOT2 1
static __device__ __forceinline__ float dot2bf(unsigned int a, unsigned int b, float c) {
    return __builtin_amdgcn_fdot2_f32_bf16(__builtin_bit_cast(bf16x2_t, a),
                                           __builtin_bit_cast(bf16x2_t, b), c, false);
}
#else
#define HAVE_DOT2 0
#endif

// ---------- 1. prep: skew S and diagonal dvec ----------
__global__ void prep_kernel(const float* __restrict__ rp, const float* __restrict__ rd,
                            float* __restrict__ S, float* __restrict__ dvec) {
    int i = blockIdx.x, j = threadIdx.x;
    float v = 0.f;
    if (j > i)      v =  0.5f * rp[i * DIM + j];
    else if (j < i) v = -0.5f * rp[j * DIM + i];
    S[i * DIM + j] = v;
    if (i == 0) {
        float t = atanf(rd[j]) * 0.63661977236758134f;  // 2/pi
        dvec[j] = (1.0f + t) / (1.0f - t);
    }
}

// ---------- 2. row-per-block GEMMs ----------
__global__ __launch_bounds__(256) void gemm_plain(const float* __restrict__ A,
                                                  const float* __restrict__ B,
                                                  float* __restrict__ C) {
    int i = blockIdx.x, j = threadIdx.x;
    const float* a = A + (size_t)i * DIM;
    float acc = 0.f;
#pragma unroll 8
    for (int k = 0; k < DIM; ++k) acc += a[k] * B[k * DIM + j];
    C[i * DIM + j] = acc;
}

// U = (I + 2S + M2) @ (I + M2)
__global__ __launch_bounds__(256) void gemm_U(const float* __restrict__ S,
                                              const float* __restrict__ M2,
                                              float* __restrict__ U) {
    int i = blockIdx.x, j = threadIdx.x;
    const float* s = S + (size_t)i * DIM;
    const float* m = M2 + (size_t)i * DIM;
    float acc = 0.f;
#pragma unroll 8
    for (int k = 0; k < DIM; ++k) {
        float av = 2.f * s[k] + m[k] + ((k == i) ? 1.f : 0.f);
        acc += av * M2[k * DIM + j];
    }
    acc += 2.f * s[j] + m[j] + ((j == i) ? 1.f : 0.f);
    U[i * DIM + j] = acc;
}

// P = U @ (I + M4)
__global__ __launch_bounds__(256) void gemm_P(const float* __restrict__ U,
                                              const float* __restrict__ M4,
                                              float* __restrict__ P) {
    int i = blockIdx.x, j = threadIdx.x;
    const float* a = U + (size_t)i * DIM;
    float acc = 0.f;
#pragma unroll 8
    for (int k = 0; k < DIM; ++k) acc += a[k] * M4[k * DIM + j];
    acc += a[j];
    P[i * DIM + j] = acc;
}

// ---------- 3. Wms ----------
__global__ __launch_bounds__(256) void gemmW_kernel(const float* __restrict__ P,
                                                    const float* __restrict__ dvec,
                                                    float* __restrict__ Wms) {
    __shared__ float col[DIM];
    int i = blockIdx.x, j = threadIdx.x;
    col[j] = P[j * DIM + i] * dvec[j];
    __syncthreads();
    float acc = 0.f;
#pragma unroll 8
    for (int k = 0; k < DIM; ++k) acc += col[k] * P[k * DIM + j];
    Wms[i * DIM + j] = acc * 0.0625f;
}

// ---------- 4. g1 ----------
__global__ __launch_bounds__(256) void g1_kernel(const float* __restrict__ f1,
                                                 const float* __restrict__ Wms,
                                                 unsigned int* __restrict__ g1u) {
    __shared__ unsigned int lt[64][33];
    int b = blockIdx.z;
    int tid = threadIdx.x;
    int il = tid & 63, w = tid >> 6;
    int i = blockIdx.x * 64 + il;
    int cb = blockIdx.y * 64 + w * 16;      // wave-uniform
    const float* f1p = f1 + (size_t)b * DIM * HW + i;
    float acc[16];
#pragma unroll
    for (int c = 0; c < 16; ++c) acc[c] = 0.f;
#pragma unroll 4
    for (int cp = 0; cp < DIM; ++cp) {
        float a = f1p[(size_t)cp * HW];
        const float* wrow = Wms + cp * DIM + cb;  // wave-uniform -> scalar loads
#pragma unroll
        for (int c = 0; c < 16; ++c) acc[c] += a * wrow[c];
    }
#pragma unroll
    for (int m = 0; m < 8; ++m) {
        unsigned int u = (unsigned int)f2bf(acc[2 * m]) | ((unsigned int)f2bf(acc[2 * m + 1]) << 16);
        lt[il][w * 8 + m] = u;
    }
    __syncthreads();
    unsigned int* dst = g1u + ((size_t)b * HW + blockIdx.x * 64) * 128 + blockIdx.y * 32;
#pragma unroll
    for (int j2 = 0; j2 < 8; ++j2) {
        int idx = tid + 256 * j2;
        int row = idx >> 5, cu = idx & 31;
        dst[(size_t)row * 128 + cu] = lt[row][cu];
    }
}

// ---------- 5. pool ----------
__global__ __launch_bounds__(256) void pool_kernel(const float* __restrict__ f2,
                                                   unsigned short* __restrict__ t) {
    __shared__ unsigned short tile[64][258];
    int b = blockIdx.y;
    int r = blockIdx.x;
    int lvl, y;
    if (r < 64)       { lvl = 0; y = r; }
    else if (r < 96)  { lvl = 1; y = r - 64; }
    else if (r < 112) { lvl = 2; y = r - 96; }
    else              { lvl = 3; y = r - 112; }
    int wl = 64 >> lvl;
    int s = 1 << lvl;
    int shift = 6 - lvl;
    int ncg = 4 << lvl;
    float inv = 1.0f / (float)(s * s);
    int tid = threadIdx.x;
    int xl = tid & (wl - 1);
    int cg = tid >> shift;

    for (int c = cg; c < DIM; c += ncg) {
        const float* src = f2 + (((size_t)b * DIM + c) * HH + y * s) * WW + xl * s;
        float acc = 0.f;
        for (int dy = 0; dy < s; ++dy) {
            const float* rowp = src + dy * WW;
            if (s == 1)      acc += rowp[0];
            else if (s == 2) { float2 v = *(const float2*)rowp; acc += v.x + v.y; }
            else if (s == 4) { float4 v = *(const float4*)rowp; acc += v.x + v.y + v.z + v.w; }
            else             { float4 v0 = *(const float4*)rowp; float4 v1 = *(const float4*)(rowp + 4);
                               acc += (v0.x + v0.y + v0.z + v0.w) + (v1.x + v1.y + v1.z + v1.w); }
        }
        tile[xl][c] = f2bf(acc * inv);
    }
    __syncthreads();
    unsigned short* dstbase = t + c_toff[lvl] + (((size_t)b * wl + y) * (size_t)wl) * DIM;
    int cu = tid & 127, xr = tid >> 7;
    for (int p0 = 0; p0 < wl; p0 += 2) {
        int xw = p0 + xr;
        unsigned int val = (unsigned int)tile[xw][2 * cu] | ((unsigned int)tile[xw][2 * cu + 1] << 16);
        *(unsigned int*)(dstbase + (size_t)xw * DIM + 2 * cu) = val;
    }
}

// ---------- 6. sampler v6: wave-per-query, offset table, quad dots ----------
__global__ __launch_bounds__(256) void sample_kernel(const unsigned short* __restrict__ g1,
                                                     const unsigned short* __restrict__ t,
                                                     const float* __restrict__ coords,
                                                     float* __restrict__ out) {
    __shared__ int   offs[QB][401];
    __shared__ float Dl[QB][401];
    __shared__ float cxs[QB], cys[QB];

    int bid = blockIdx.x;
    int swz = (bid & 7) * 256 + (bid >> 3);   // bijective XCD swizzle, 2048 blocks
    int qbase = swz * QB;
    int b = qbase >> 12, y = (qbase >> 6) & 63, x0 = qbase & 63;
    int tid = threadIdx.x;
    int w = tid >> 6;          // wave index = local query
    int l = tid & 63;

    // per-wave coords (same address for all lanes -> broadcast)
    float cx = coords[(((size_t)b * 2 + 0) * HH + y) * WW + (x0 + w)];
    float cy = coords[(((size_t)b * 2 + 1) * HH + y) * WW + (x0 + w)];
    if (l == 0) { cxs[w] = cx; cys[w] = cy; }

    // build offset table for this wave's query (wave-coherent LDS, no barrier needed)
#pragma unroll
    for (int i = 0; i < 7; ++i) {
        int p = l + 64 * i;
        if (p < 400) {
            int lvl = p / 100, rem = p % 100;
            int u = rem / 10, v = rem % 10;
            float scale = 1.0f / (float)(1 << lvl);
            int X0 = (int)floorf(cx * scale), Y0 = (int)floorf(cy * scale);
            int wl = 64 >> lvl;
            int xi = X0 - 4 + u, yi = Y0 - 4 + v;
            int off = -1;
            if (xi >= 0 && xi < wl && yi >= 0 && yi < wl)
                off = (int)(c_toff[lvl] * 2) + (((b * wl + yi) * wl + xi) * (DIM * 2));
            offs[w][p] = off;
        }
    }

    // g1 fragment pinned in registers: row qbase+w, lane-quarter j=(l&3) covers
    // bytes {j*16 + i*64}, i=0..7  (matches the t-load pattern below)
    const uint4* grow = (const uint4*)(g1 + (size_t)(qbase + w) * DIM);
    uint4 gfrag[8];
#pragma unroll
    for (int i = 0; i < 8; ++i) gfrag[i] = grow[(l & 3) + i * 4];

    // main loop: 25 iters x 16 dots/wave; quad (4 lanes) per dot
    for (int it = 0; it < 25; ++it) {
        int p = it * 16 + (l >> 2);
        int off = offs[w][p];
        float r = 0.f;
        if (off >= 0) {
            const uint4* tv = (const uint4*)((const char*)t + off);
#if HAVE_DOT2
            float a0 = 0.f, a1 = 0.f, a2 = 0.f, a3 = 0.f;
#pragma unroll
            for (int i = 0; i < 8; ++i) {
                uint4 wv = tv[(l & 3) + i * 4];   // quad covers 64B contiguous per i
                a0 = dot2bf(wv.x, gfrag[i].x, a0);
                a1 = dot2bf(wv.y, gfrag[i].y, a1);
                a2 = dot2bf(wv.z, gfrag[i].z, a2);
                a3 = dot2bf(wv.w, gfrag[i].w, a3);
            }
            r = (a0 + a1) + (a2 + a3);
#else
            float a0 = 0.f, a1 = 0.f, a2 = 0.f, a3 = 0.f;
#pragma unroll
            for (int i = 0; i < 8; ++i) {
                uint4 wv = tv[(l & 3) + i * 4];
                a0 += bflo(wv.x) * bflo(gfrag[i].x) + bfhi(wv.x) * bfhi(gfrag[i].x);
                a1 += bflo(wv.y) * bflo(gfrag[i].y) + bfhi(wv.y) * bfhi(gfrag[i].y);
                a2 += bflo(wv.z) * bflo(gfrag[i].z) + bfhi(wv.z) * bfhi(gfrag[i].z);
                a3 += bflo(wv.w) * bflo(gfrag[i].w) + bfhi(wv.w) * bfhi(gfrag[i].w);
            }
            r = (a0 + a1) + (a2 + a3);
#endif
        }
        // 2-step quad reduce
        r += __shfl_xor(r, 1);
        r += __shfl_xor(r, 2);
        if ((l & 3) == 0) Dl[w][p] = r;
    }
    __syncthreads();

    // phase 2: QB*324 outputs; idx = ch*QB + q
    for (int idx = tid; idx < QB * NCH; idx += 256) {
        int ch = idx >> 2, qq = idx & (QB - 1);
        int lvl = ch / 81, rem2 = ch % 81;
        int a = rem2 / 9, bb = rem2 % 9;
        float cx2 = cxs[qq], cy2 = cys[qq];
        float scale = 1.0f / (float)(1 << lvl);
        float cxl = cx2 * scale, cyl = cy2 * scale;
        float fx = cxl - floorf(cxl), fy = cyl - floorf(cyl);
        float wx0 = 1.f - fx, wy0 = 1.f - fy;
        int base = lvl * 100 + a * 10 + bb;
        float v00 = Dl[qq][base],     v10 = Dl[qq][base + 10];
        float v01 = Dl[qq][base + 1], v11 = Dl[qq][base + 11];
        float val = wy0 * (wx0 * v00 + fx * v10) + fy * (wx0 * v01 + fx * v11);
        out[(((size_t)b * NCH + ch) * HH + y) * WW + (x0 + qq)] = val;
    }
}

extern "C" void kernel_launch(void* const* d_in, const int* in_sizes, int n_in,
                              void* d_out, int out_size, void* d_ws, size_t ws_size,
                              hipStream_t stream) {
    const float* f1     = (const float*)d_in[0];
    const float* f2     = (const float*)d_in[1];
    const float* coords = (const float*)d_in[2];
    const float* rp     = (const float*)d_in[3];
    const float* rd     = (const float*)d_in[4];
    float* out = (float*)d_out;

    // workspace carve (floats)
    float* S    = (float*)d_ws;
    float* M2   = S   + 65536;
    float* M4   = M2  + 65536;
    float* Um   = M4  + 65536;
    float* Pm   = Um  + 65536;
    float* Wms  = Pm  + 65536;
    float* dvec = Wms + 65536;                               // 256 floats
    unsigned short* g1 = (unsigned short*)(dvec + 256);      // 2*4096*256 bf16
    unsigned short* t  = g1 + (size_t)NB * HW * DIM;         // 2785280 bf16

    prep_kernel<<<256, 256, 0, stream>>>(rp, rd, S, dvec);
    gemm_plain<<<256, 256, 0, stream>>>(S,  S,  M2);     // S^2
    gemm_plain<<<256, 256, 0, stream>>>(M2, M2, M4);     // S^4
    gemm_U    <<<256, 256, 0, stream>>>(S,  M2, Um);     // (I+S)^2 (I+S^2)
    gemm_P    <<<256, 256, 0, stream>>>(Um, M4, Pm);     // * (I+S^4) = P
    gemmW_kernel<<<256, 256, 0, stream>>>(Pm, dvec, Wms);

    g1_kernel<<<dim3(64, 4, 2), 256, 0, stream>>>(f1, Wms, (unsigned int*)g1);
    pool_kernel<<<dim3(120, 2), 256, 0, stream>>>(f2, t);
    sample_kernel<<<NQ / QB, 256, 0, stream>>>(g1, t, coords, out);
}